// Round 5
// baseline (82.528 us; speedup 1.0000x reference)
//
#include <hip/hip_runtime.h>
#include <hip/hip_bf16.h>
#include <math.h>

#define B_   32
#define D_   128
#define L_   512
#define NH_  8
#define DK_  16

#define QKS  18    // Qt row stride in f16 elems ([512][16] + pad 2) - odd dword stride
#define VST  520   // V row stride ([16][512] + pad 8)
#define SST  38    // S row stride ([32][32] + pad 6), per-wave - odd dword stride

#define LOG2E 1.4426950408889634f
#define SH2  (-11.541560327111707f)   // -8 * log2(e): fixed softmax shift of 8

typedef _Float16 h4 __attribute__((ext_vector_type(4)));
typedef _Float16 h8 __attribute__((ext_vector_type(8)));
typedef __attribute__((ext_vector_type(4))) float f32x4;

#define MFMA_K32(a, b, c) __builtin_amdgcn_mfma_f32_16x16x32_f16((a), (b), (c), 0, 0, 0)
#define MFMA_K16(a, b, c) __builtin_amdgcn_mfma_f32_16x16x16f16((a), (b), (c), 0, 0, 0)

// ---------------------------------------------------------------------------
// Kernel 0: xt[b][l][d] = (fp16) x[b][d][l]  — LDS-tiled transpose+cast.
// grid (8 l-tiles, 32 b), 256 threads. Both global sides fully coalesced.
// ---------------------------------------------------------------------------
__global__ __launch_bounds__(256) void xcast(
    const float* __restrict__ x,   // [B][D][L]
    _Float16* __restrict__ xt)     // [B][L][D]
{
    __shared__ _Float16 T[64][130];   // stride 130: 65 dwords, conflict-free
    const int lt = blockIdx.x;
    const int b  = blockIdx.y;
    const int t  = threadIdx.x;
    const float* xb = x + (size_t)b * D_ * L_;
    _Float16* xtb = xt + (size_t)b * L_ * D_;

    #pragma unroll
    for (int i = t; i < 64 * 128; i += 256) {
        const int l = i & 63, d = i >> 6;
        T[l][d] = (_Float16)xb[(size_t)d * L_ + lt * 64 + l];
    }
    __syncthreads();
    #pragma unroll
    for (int i = t; i < 64 * 128; i += 256) {
        const int d = i & 127, l = i >> 7;
        xtb[(size_t)(lt * 64 + l) * D_ + d] = T[l][d];
    }
}

// ---------------------------------------------------------------------------
// Kernel A: fused per-(head,batch) attention, all-fp16 MFMA, fixed-shift
// softmax. grid 256 = (n,b), 1024 threads = 16 waves (4 waves/SIMD).
// Wave w owns m-span [32w, 32w+32) (2 m-tiles) and P1 l-tiles {2w, 2w+1}.
// K stays in registers (16x16x16 B-frag layout == P1 D-frag layout).
// ---------------------------------------------------------------------------
__global__ __launch_bounds__(1024, 4) void attn_mfma(
    const _Float16* __restrict__ xt,  // [B][L][D] fp16
    const float* __restrict__ Wq,     // [NH][B][DK][D]
    const float* __restrict__ Wk,
    const float* __restrict__ Wv,
    _Float16* __restrict__ Ht)        // [B][512][128] fp16 (transposed heads)
{
    __shared__ __attribute__((aligned(16))) _Float16 Qh[512 * QKS];    // 18.4 KB
    __shared__ __attribute__((aligned(16))) _Float16 Vs[16 * VST];     // 16.6 KB
    __shared__ __attribute__((aligned(16))) _Float16 Sl[16][32 * SST]; // 38.9 KB

    const int nb = blockIdx.x;
    const int n  = nb >> 5;
    const int b  = nb & 31;
    const int t  = threadIdx.x;
    const int wv = t >> 6;          // wave 0..15
    const int ln = t & 63;
    const int l16 = ln & 15;
    const int g4  = ln >> 4;        // 0..3

    const _Float16* xtb = xt + (size_t)b * L_ * D_;
    const size_t woff = (size_t)(n * B_ + b) * DK_ * D_;
    const float* pWq = Wq + woff;
    const float* pWk = Wk + woff;
    const float* pWv = Wv + woff;

    // ================= P1: Q,K,V = W @ x  (fp16 MFMA) =====================
    f32x4 Qa[2], Ka[2], Va[2];
    #pragma unroll
    for (int lt = 0; lt < 2; ++lt) {
        Qa[lt] = (f32x4){0.f,0.f,0.f,0.f};
        Ka[lt] = (f32x4){0.f,0.f,0.f,0.f};
        Va[lt] = (f32x4){0.f,0.f,0.f,0.f};
    }

    #pragma unroll
    for (int ks = 0; ks < 4; ++ks) {
        const int d0 = ks * 32 + g4 * 8;       // A/B-frag k = 8*g4 + j
        const float* aq = pWq + l16 * D_ + d0;
        const float* ak = pWk + l16 * D_ + d0;
        const float* av = pWv + l16 * D_ + d0;
        const float4 q0 = *(const float4*)aq, q1 = *(const float4*)(aq + 4);
        const float4 k0 = *(const float4*)ak, k1 = *(const float4*)(ak + 4);
        const float4 v0 = *(const float4*)av, v1 = *(const float4*)(av + 4);
        h8 Aq, Ak, Av;
        Aq[0]=(_Float16)q0.x; Aq[1]=(_Float16)q0.y; Aq[2]=(_Float16)q0.z; Aq[3]=(_Float16)q0.w;
        Aq[4]=(_Float16)q1.x; Aq[5]=(_Float16)q1.y; Aq[6]=(_Float16)q1.z; Aq[7]=(_Float16)q1.w;
        Ak[0]=(_Float16)k0.x; Ak[1]=(_Float16)k0.y; Ak[2]=(_Float16)k0.z; Ak[3]=(_Float16)k0.w;
        Ak[4]=(_Float16)k1.x; Ak[5]=(_Float16)k1.y; Ak[6]=(_Float16)k1.z; Ak[7]=(_Float16)k1.w;
        Av[0]=(_Float16)v0.x; Av[1]=(_Float16)v0.y; Av[2]=(_Float16)v0.z; Av[3]=(_Float16)v0.w;
        Av[4]=(_Float16)v1.x; Av[5]=(_Float16)v1.y; Av[6]=(_Float16)v1.z; Av[7]=(_Float16)v1.w;
        #pragma unroll
        for (int lt = 0; lt < 2; ++lt) {
            const int l = wv * 32 + lt * 16 + l16;
            const h8 Bx = *(const h8*)&xtb[(size_t)l * D_ + d0];
            Qa[lt] = MFMA_K32(Aq, Bx, Qa[lt]);
            Ka[lt] = MFMA_K32(Ak, Bx, Ka[lt]);
            Va[lt] = MFMA_K32(Av, Bx, Va[lt]);
        }
    }

    // K stays in registers: D-frag (col l, row k=4g4+r) IS the 16x16x16
    // B-frag (col=l16, k=4g4+j). Q -> LDS transposed; V -> LDS [v][l].
    h4 Kreg[2];
    #pragma unroll
    for (int lt = 0; lt < 2; ++lt) {
        const int l = wv * 32 + lt * 16 + l16;
        h4 qv;
        #pragma unroll
        for (int r = 0; r < 4; ++r) {
            qv[r]       = (_Float16)(Qa[lt][r] * 0.25f);   // fold 1/sqrt(dk)
            Kreg[lt][r] = (_Float16)Ka[lt][r];
            Vs[(g4 * 4 + r) * VST + l] = (_Float16)Va[lt][r];
        }
        *(h4*)&Qh[l * QKS + g4 * 4] = qv;
    }
    __syncthreads();

    // ================= P2: attention, fixed-shift softmax =================
    f32x4 pv[2];
    float Zp[2];
    #pragma unroll
    for (int mt = 0; mt < 2; ++mt) {
        pv[mt] = (f32x4){0.f,0.f,0.f,0.f};
        Zp[mt] = 0.f;
    }
    _Float16* mySl = &Sl[wv][0];

    for (int t32 = 0; t32 < 16; ++t32) {
        const int lb = t32 * 32;
        const h4 qa0 = *(const h4*)&Qh[(lb + l16) * QKS + g4 * 4];
        const h4 qa1 = *(const h4*)&Qh[(lb + 16 + l16) * QKS + g4 * 4];

        #pragma unroll
        for (int mt = 0; mt < 2; ++mt) {
            f32x4 s0 = (f32x4){0.f,0.f,0.f,0.f};
            f32x4 s1 = (f32x4){0.f,0.f,0.f,0.f};
            s0 = MFMA_K16(qa0, Kreg[mt], s0);
            s1 = MFMA_K16(qa1, Kreg[mt], s1);

            h4 p0h, p1h;
            float zs = 0.f;
            #pragma unroll
            for (int r = 0; r < 4; ++r) {
                float p = exp2f(fmaf(s0[r], LOG2E, SH2));
                zs += p; p0h[r] = (_Float16)p;
            }
            #pragma unroll
            for (int r = 0; r < 4; ++r) {
                float p = exp2f(fmaf(s1[r], LOG2E, SH2));
                zs += p; p1h[r] = (_Float16)p;
            }
            Zp[mt] += zs;
            // stored[m_local][l_local] (= S^T): rows m, cols l
            *(h4*)&mySl[(mt * 16 + l16) * SST + g4 * 4]      = p0h;
            *(h4*)&mySl[(mt * 16 + l16) * SST + 16 + g4 * 4] = p1h;
        }
        // wave-private S: fence cross-lane LDS write->read
        asm volatile("s_waitcnt lgkmcnt(0)" ::: "memory");
        const h8 aV = *(const h8*)&Vs[l16 * VST + lb + g4 * 8];
        #pragma unroll
        for (int mt = 0; mt < 2; ++mt) {
            const h8 bS = *(const h8*)&mySl[(mt * 16 + l16) * SST + g4 * 8];
            pv[mt] = MFMA_K32(aV, bS, pv[mt]);
        }
    }

    // epilogue: cross-lane Z reduce, normalize, write transposed +
    // head-reversed fp16: Ht[b][m][ (NH-1-n)*16 + 4g4+r ]
    const size_t hbase = (size_t)b * 512 * 128 + (size_t)(NH_ - 1 - n) * 16 + g4 * 4;
    #pragma unroll
    for (int mt = 0; mt < 2; ++mt) {
        float z = Zp[mt];
        z += __shfl_xor(z, 16);
        z += __shfl_xor(z, 32);
        const float rz = 1.f / z;
        const int m = wv * 32 + mt * 16 + l16;
        h4 hv;
        #pragma unroll
        for (int r = 0; r < 4; ++r)
            hv[r] = (_Float16)(pv[mt][r] * rz);
        *(h4*)&Ht[hbase + (size_t)m * 128] = hv;
    }
}

// ---------------------------------------------------------------------------
// Kernel B: out[b] = Wo[b] (128x128) @ heads[b] (128x512), fp16 MFMA,
// pure-register. grid (8 col-tiles, 32 b), 512 thr; wave = 16-row m-tile.
// ---------------------------------------------------------------------------
__global__ __launch_bounds__(512) void out_proj_mfma(
    const float* __restrict__ Wo,        // [B][128][128]
    const _Float16* __restrict__ Ht,     // [B][512][128]
    float* __restrict__ out)             // [B][128][512]
{
    const int ct = blockIdx.x;     // col0 = ct*64
    const int b  = blockIdx.y;
    const int t  = threadIdx.x;
    const int wv = t >> 6;
    const int ln = t & 63;
    const int l16 = ln & 15;
    const int g4  = ln >> 4;

    const float* Wb = Wo + (size_t)b * D_ * D_;
    const _Float16* Hb = Ht + (size_t)b * 512 * 128;

    f32x4 acc[4];
    #pragma unroll
    for (int nt = 0; nt < 4; ++nt) acc[nt] = (f32x4){0.f,0.f,0.f,0.f};

    #pragma unroll
    for (int ks = 0; ks < 4; ++ks) {
        const int k0 = ks * 32 + g4 * 8;
        const float* ap = Wb + (size_t)(wv * 16 + l16) * D_ + k0;
        h8 Ah;
        #pragma unroll
        for (int j = 0; j < 8; ++j) Ah[j] = (_Float16)ap[j];
        #pragma unroll
        for (int nt = 0; nt < 4; ++nt) {
            const h8 Bh = *(const h8*)&Hb[(size_t)(ct * 64 + nt * 16 + l16) * 128 + k0];
            acc[nt] = MFMA_K32(Ah, Bh, acc[nt]);
        }
    }

    float* ob = out + (size_t)b * D_ * L_;
    #pragma unroll
    for (int nt = 0; nt < 4; ++nt) {
        #pragma unroll
        for (int r = 0; r < 4; ++r) {
            ob[(size_t)(wv * 16 + g4 * 4 + r) * L_ + ct * 64 + nt * 16 + l16] = acc[nt][r];
        }
    }
}

extern "C" void kernel_launch(void* const* d_in, const int* in_sizes, int n_in,
                              void* d_out, int out_size, void* d_ws, size_t ws_size,
                              hipStream_t stream)
{
    const float* x  = (const float*)d_in[0];
    const float* Wq = (const float*)d_in[1];
    const float* Wk = (const float*)d_in[2];
    const float* Wv = (const float*)d_in[3];
    const float* Wo = (const float*)d_in[4];
    float* out = (float*)d_out;

    _Float16* Ht = (_Float16*)d_ws;                       // 4 MB
    _Float16* xt = Ht + (size_t)B_ * 512 * 128;           // 4 MB

    xcast<<<dim3(8, B_), dim3(256), 0, stream>>>(x, xt);
    attn_mfma<<<dim3(NH_ * B_), dim3(1024), 0, stream>>>(xt, Wq, Wk, Wv, Ht);
    out_proj_mfma<<<dim3(8, B_), dim3(512), 0, stream>>>(Wo, Ht, out);
}

// Round 7
// 53.768 us; speedup vs baseline: 1.5349x; 1.5349x over previous
//
#include <hip/hip_runtime.h>
#include <hip/hip_bf16.h>
#include <math.h>

#define B_   32
#define D_   128
#define L_   512
#define NH_  8
#define DK_  16

#define QKS  18    // Qt row stride in f16 elems ([512][16] + pad 2) - odd dword stride
#define VST  520   // V row stride ([16][512] + pad 8)

#define LOG2E 1.4426950408889634f
#define SH2  (-11.541560327111707f)   // -8 * log2(e): fixed softmax shift of 8

typedef _Float16 h2 __attribute__((ext_vector_type(2)));
typedef _Float16 h4 __attribute__((ext_vector_type(4)));
typedef _Float16 h8 __attribute__((ext_vector_type(8)));
typedef __attribute__((ext_vector_type(4))) float f32x4;

__device__ __forceinline__ h2 cvt_pk(float a, float b) {
    return __builtin_bit_cast(h2, __builtin_amdgcn_cvt_pkrtz(a, b));
}

#define MFMA_K32(a, b, c) __builtin_amdgcn_mfma_f32_16x16x32_f16((a), (b), (c), 0, 0, 0)
#define MFMA_K16(a, b, c) __builtin_amdgcn_mfma_f32_16x16x16f16((a), (b), (c), 0, 0, 0)

// ---------------------------------------------------------------------------
// Kernel 0: xt[b][l][d] = (fp16) x[b][d][l]  — LDS-tiled transpose+cast.
// ---------------------------------------------------------------------------
__global__ __launch_bounds__(256) void xcast(
    const float* __restrict__ x,   // [B][D][L]
    _Float16* __restrict__ xt)     // [B][L][D]
{
    __shared__ _Float16 T[64][130];
    const int lt = blockIdx.x;
    const int b  = blockIdx.y;
    const int t  = threadIdx.x;
    const float* xb = x + (size_t)b * D_ * L_;
    _Float16* xtb = xt + (size_t)b * L_ * D_;

    #pragma unroll
    for (int i = t; i < 64 * 128; i += 256) {
        const int l = i & 63, d = i >> 6;
        T[l][d] = (_Float16)xb[(size_t)d * L_ + lt * 64 + l];
    }
    __syncthreads();
    #pragma unroll
    for (int i = t; i < 64 * 128; i += 256) {
        const int d = i & 127, l = i >> 7;
        xtb[(size_t)(lt * 64 + l) * D_ + d] = T[l][d];
    }
}

// ---------------------------------------------------------------------------
// Kernel A: fused per-(head,batch) attention, all-fp16 MFMA, fixed-shift
// softmax, REGISTER-RESIDENT P (QK^T D-frag == PV A-frag for 16x16x16):
// no S LDS buffer, no lgkmcnt drain, no scheduling barrier in the loop.
// grid 256 = (n,b), 1024 threads = 16 waves. Wave w: m-span [32w, 32w+32).
// ---------------------------------------------------------------------------
__global__ __launch_bounds__(1024, 4) void attn_mfma(
    const _Float16* __restrict__ xt,  // [B][L][D] fp16
    const float* __restrict__ Wq,     // [NH][B][DK][D]
    const float* __restrict__ Wk,
    const float* __restrict__ Wv,
    _Float16* __restrict__ Ht)        // [B][512][128] fp16 (transposed heads)
{
    __shared__ __attribute__((aligned(16))) _Float16 Qh[512 * QKS];  // 18.4 KB
    __shared__ __attribute__((aligned(16))) _Float16 Vs[16 * VST];   // 16.6 KB

    const int nb = blockIdx.x;
    const int n  = nb >> 5;
    const int b  = nb & 31;
    const int t  = threadIdx.x;
    const int wv = t >> 6;          // wave 0..15
    const int ln = t & 63;
    const int l16 = ln & 15;
    const int g4  = ln >> 4;        // 0..3

    const _Float16* xtb = xt + (size_t)b * L_ * D_;
    const size_t woff = (size_t)(n * B_ + b) * DK_ * D_;
    const float* pWq = Wq + woff;
    const float* pWk = Wk + woff;
    const float* pWv = Wv + woff;

    // ================= P1: Q,K,V = W @ x  (fp16 MFMA) =====================
    f32x4 Qa[2], Ka[2], Va[2];
    #pragma unroll
    for (int lt = 0; lt < 2; ++lt) {
        Qa[lt] = (f32x4){0.f,0.f,0.f,0.f};
        Ka[lt] = (f32x4){0.f,0.f,0.f,0.f};
        Va[lt] = (f32x4){0.f,0.f,0.f,0.f};
    }

    #pragma unroll
    for (int ks = 0; ks < 4; ++ks) {
        const int d0 = ks * 32 + g4 * 8;       // A/B-frag k = 8*g4 + j
        const float* aq = pWq + l16 * D_ + d0;
        const float* ak = pWk + l16 * D_ + d0;
        const float* av = pWv + l16 * D_ + d0;
        const float4 q0 = *(const float4*)aq, q1 = *(const float4*)(aq + 4);
        const float4 k0 = *(const float4*)ak, k1 = *(const float4*)(ak + 4);
        const float4 v0 = *(const float4*)av, v1 = *(const float4*)(av + 4);
        h8 Aq, Ak, Av;
        Aq[0]=(_Float16)q0.x; Aq[1]=(_Float16)q0.y; Aq[2]=(_Float16)q0.z; Aq[3]=(_Float16)q0.w;
        Aq[4]=(_Float16)q1.x; Aq[5]=(_Float16)q1.y; Aq[6]=(_Float16)q1.z; Aq[7]=(_Float16)q1.w;
        Ak[0]=(_Float16)k0.x; Ak[1]=(_Float16)k0.y; Ak[2]=(_Float16)k0.z; Ak[3]=(_Float16)k0.w;
        Ak[4]=(_Float16)k1.x; Ak[5]=(_Float16)k1.y; Ak[6]=(_Float16)k1.z; Ak[7]=(_Float16)k1.w;
        Av[0]=(_Float16)v0.x; Av[1]=(_Float16)v0.y; Av[2]=(_Float16)v0.z; Av[3]=(_Float16)v0.w;
        Av[4]=(_Float16)v1.x; Av[5]=(_Float16)v1.y; Av[6]=(_Float16)v1.z; Av[7]=(_Float16)v1.w;
        #pragma unroll
        for (int lt = 0; lt < 2; ++lt) {
            const int l = wv * 32 + lt * 16 + l16;
            const h8 Bx = *(const h8*)&xtb[(size_t)l * D_ + d0];
            Qa[lt] = MFMA_K32(Aq, Bx, Qa[lt]);
            Ka[lt] = MFMA_K32(Ak, Bx, Ka[lt]);
            Va[lt] = MFMA_K32(Av, Bx, Va[lt]);
        }
    }

    // K stays in registers (D-frag == 16x16x16 B-frag). Q^T, V -> LDS.
    h4 Kreg[2];
    #pragma unroll
    for (int lt = 0; lt < 2; ++lt) {
        const int l = wv * 32 + lt * 16 + l16;
        h4 qv;
        #pragma unroll
        for (int r = 0; r < 4; ++r) {
            qv[r]       = (_Float16)(Qa[lt][r] * 0.25f);   // fold 1/sqrt(dk)
            Kreg[lt][r] = (_Float16)Ka[lt][r];
            Vs[(g4 * 4 + r) * VST + l] = (_Float16)Va[lt][r];
        }
        *(h4*)&Qh[l * QKS + g4 * 4] = qv;
    }
    __syncthreads();

    // ================= P2: attention, P register-resident ================
    f32x4 pv[2];           // D' accum: (m_local = 4g4+r, v = l16) per mt
    float Zp[2];
    #pragma unroll
    for (int mt = 0; mt < 2; ++mt) {
        pv[mt] = (f32x4){0.f,0.f,0.f,0.f};
        Zp[mt] = 0.f;
    }

    #pragma unroll 2
    for (int t32 = 0; t32 < 16; ++t32) {
        const int lb = t32 * 32;
        // A-frags of QK^T (rows = l) and B-frags of PV (V[v=l16][lb+4g4+j])
        const h4 qa0 = *(const h4*)&Qh[(lb + l16) * QKS + g4 * 4];
        const h4 qa1 = *(const h4*)&Qh[(lb + 16 + l16) * QKS + g4 * 4];
        const h4 bV0 = *(const h4*)&Vs[l16 * VST + lb + g4 * 4];
        const h4 bV1 = *(const h4*)&Vs[l16 * VST + lb + 16 + g4 * 4];

        #pragma unroll
        for (int mt = 0; mt < 2; ++mt) {
            f32x4 s0 = (f32x4){0.f,0.f,0.f,0.f};
            f32x4 s1 = (f32x4){0.f,0.f,0.f,0.f};
            s0 = MFMA_K16(qa0, Kreg[mt], s0);   // P(lb+4g4+r,  m=m_base+l16)
            s1 = MFMA_K16(qa1, Kreg[mt], s1);   // P(lb+16+4g4+r, ")

            float p0[4], p1[4], zs = 0.f;
            #pragma unroll
            for (int r = 0; r < 4; ++r) {
                p0[r] = exp2f(fmaf(s0[r], LOG2E, SH2)); zs += p0[r];
            }
            #pragma unroll
            for (int r = 0; r < 4; ++r) {
                p1[r] = exp2f(fmaf(s1[r], LOG2E, SH2)); zs += p1[r];
            }
            Zp[mt] += zs;

            // P -> fp16 A-frags (layout already matches: row=m=l16, k=l=4g4+j)
            const h2 a0 = cvt_pk(p0[0], p0[1]);
            const h2 a1 = cvt_pk(p0[2], p0[3]);
            const h2 a2 = cvt_pk(p1[0], p1[1]);
            const h2 a3 = cvt_pk(p1[2], p1[3]);
            const h4 pa0 = __builtin_shufflevector(a0, a1, 0, 1, 2, 3);
            const h4 pa1 = __builtin_shufflevector(a2, a3, 0, 1, 2, 3);

            pv[mt] = MFMA_K16(pa0, bV0, pv[mt]);  // D'(m_local, v)
            pv[mt] = MFMA_K16(pa1, bV1, pv[mt]);
        }
    }

    // epilogue: Z butterfly (group of 4 lanes), redistribute Z to rows,
    // write head-reversed transposed fp16: Ht[b][m][(NH-1-n)*16 + v]
    const int kk = (NH_ - 1 - n) * 16 + l16;
    _Float16* Hb = Ht + (size_t)b * 512 * 128;
    #pragma unroll
    for (int mt = 0; mt < 2; ++mt) {
        float z = Zp[mt];
        z += __shfl_xor(z, 16);
        z += __shfl_xor(z, 32);
        const float rz = 1.f / z;          // valid for m_local = l16
        const int m_base = wv * 32 + mt * 16;
        #pragma unroll
        for (int r = 0; r < 4; ++r) {
            const float rzr = __shfl(rz, 4 * g4 + r);   // Z for m_local=4g4+r
            Hb[(size_t)(m_base + 4 * g4 + r) * 128 + kk] =
                (_Float16)(pv[mt][r] * rzr);
        }
    }
}

// ---------------------------------------------------------------------------
// Kernel B: out[b] = Wo[b] (128x128) @ heads[b] (128x512), fp16 MFMA,
// pure-register. grid (8 col-tiles, 32 b), 512 thr; wave = 16-row m-tile.
// ---------------------------------------------------------------------------
__global__ __launch_bounds__(512) void out_proj_mfma(
    const float* __restrict__ Wo,        // [B][128][128]
    const _Float16* __restrict__ Ht,     // [B][512][128]
    float* __restrict__ out)             // [B][128][512]
{
    const int ct = blockIdx.x;     // col0 = ct*64
    const int b  = blockIdx.y;
    const int t  = threadIdx.x;
    const int wv = t >> 6;
    const int ln = t & 63;
    const int l16 = ln & 15;
    const int g4  = ln >> 4;

    const float* Wb = Wo + (size_t)b * D_ * D_;
    const _Float16* Hb = Ht + (size_t)b * 512 * 128;

    f32x4 acc[4];
    #pragma unroll
    for (int nt = 0; nt < 4; ++nt) acc[nt] = (f32x4){0.f,0.f,0.f,0.f};

    #pragma unroll
    for (int ks = 0; ks < 4; ++ks) {
        const int k0 = ks * 32 + g4 * 8;
        const float* ap = Wb + (size_t)(wv * 16 + l16) * D_ + k0;
        h8 Ah;
        #pragma unroll
        for (int j = 0; j < 8; ++j) Ah[j] = (_Float16)ap[j];
        #pragma unroll
        for (int nt = 0; nt < 4; ++nt) {
            const h8 Bh = *(const h8*)&Hb[(size_t)(ct * 64 + nt * 16 + l16) * 128 + k0];
            acc[nt] = MFMA_K32(Ah, Bh, acc[nt]);
        }
    }

    float* ob = out + (size_t)b * D_ * L_;
    #pragma unroll
    for (int nt = 0; nt < 4; ++nt) {
        #pragma unroll
        for (int r = 0; r < 4; ++r) {
            ob[(size_t)(wv * 16 + g4 * 4 + r) * L_ + ct * 64 + nt * 16 + l16] = acc[nt][r];
        }
    }
}

extern "C" void kernel_launch(void* const* d_in, const int* in_sizes, int n_in,
                              void* d_out, int out_size, void* d_ws, size_t ws_size,
                              hipStream_t stream)
{
    const float* x  = (const float*)d_in[0];
    const float* Wq = (const float*)d_in[1];
    const float* Wk = (const float*)d_in[2];
    const float* Wv = (const float*)d_in[3];
    const float* Wo = (const float*)d_in[4];
    float* out = (float*)d_out;

    _Float16* Ht = (_Float16*)d_ws;                       // 4 MB
    _Float16* xt = Ht + (size_t)B_ * 512 * 128;           // 4 MB

    xcast<<<dim3(8, B_), dim3(256), 0, stream>>>(x, xt);
    attn_mfma<<<dim3(NH_ * B_), dim3(1024), 0, stream>>>(xt, Wq, Wk, Wv, Ht);
    out_proj_mfma<<<dim3(8, B_), dim3(512), 0, stream>>>(Wo, Ht, out);
}